// Round 1
// baseline (2407.826 us; speedup 1.0000x reference)
//
#include <hip/hip_runtime.h>
#include <hip/hip_bf16.h>

#define H 24
#define HD 128
#define DMODEL 3072
#define S_IMG 2048
#define S_TXT 512
#define S_ALL 2560
#define EMB 4096
#define N_IP 64
#define SM_SCALE 0.08838834764831845f  // 1/sqrt(128)

typedef __attribute__((ext_vector_type(8))) short short8;
typedef __attribute__((ext_vector_type(4))) float f32x4;

__device__ inline unsigned short f2bf(float f) {
    unsigned u = __builtin_bit_cast(unsigned, f);
    return (unsigned short)((u + 0x7fffu + ((u >> 16) & 1u)) >> 16);
}
__device__ inline unsigned pk2(float a, float b) {
    return (unsigned)f2bf(a) | ((unsigned)f2bf(b) << 16);
}

// ---------------- GEMM: C[M,N] = A[M,K] @ W[N,K]^T + bias ----------------
// 128x128 tile, BK=32, 4 waves (2x2), per-wave 64x64 = 4x4 mfma_16x16x32_bf16.
// LDS tiles [128][32] bf16, row = 64B, XOR swizzle ((row>>1)&3)<<4 -> 2-way free.

__device__ inline int swz64(int row, int colb) {
    return row * 64 + (colb ^ (((row >> 1) & 3) << 4));
}

template<int ABF>
__global__ __launch_bounds__(256)
void gemm_bt(const void* __restrict__ Ap, const float* __restrict__ W,
             const float* __restrict__ bias, float* __restrict__ C,
             int M, int N, int K)
{
    __shared__ char sm[16384];
    const int tid = threadIdx.x;
    const int lane = tid & 63;
    const int wid = tid >> 6;
    const int wr = wid >> 1, wc = wid & 1;
    const int r15 = lane & 15, g = lane >> 4;
    const int m0 = blockIdx.x * 128, n0 = blockIdx.y * 128;

    f32x4 acc[4][4];
    #pragma unroll
    for (int i = 0; i < 4; i++)
        #pragma unroll
        for (int j = 0; j < 4; j++)
            acc[i][j] = {0.f, 0.f, 0.f, 0.f};

    for (int k0 = 0; k0 < K; k0 += 32) {
        if (ABF) {
            const unsigned short* A = (const unsigned short*)Ap;
            #pragma unroll
            for (int i = 0; i < 2; i++) {
                int slot = tid + 256 * i;
                int row = slot >> 2, c8 = slot & 3;
                int4 v = {0, 0, 0, 0};
                if (m0 + row < M)
                    v = *(const int4*)(A + (size_t)(m0 + row) * K + k0 + c8 * 8);
                *(int4*)(sm + swz64(row, c8 * 16)) = v;
            }
        } else {
            const float* A = (const float*)Ap;
            #pragma unroll
            for (int i = 0; i < 4; i++) {
                int slot = tid + 256 * i;
                int row = slot >> 3, c4 = slot & 7;
                float4 v = {0.f, 0.f, 0.f, 0.f};
                if (m0 + row < M)
                    v = *(const float4*)(A + (size_t)(m0 + row) * K + k0 + c4 * 4);
                uint2 p; p.x = pk2(v.x, v.y); p.y = pk2(v.z, v.w);
                *(uint2*)(sm + swz64(row, c4 * 8)) = p;
            }
        }
        #pragma unroll
        for (int i = 0; i < 4; i++) {
            int slot = tid + 256 * i;
            int row = slot >> 3, c4 = slot & 7;
            float4 v = *(const float4*)(W + (size_t)(n0 + row) * K + k0 + c4 * 4);
            uint2 p; p.x = pk2(v.x, v.y); p.y = pk2(v.z, v.w);
            *(uint2*)(sm + 8192 + swz64(row, c4 * 8)) = p;
        }
        __syncthreads();
        short8 af[4], bfr[4];
        #pragma unroll
        for (int mi = 0; mi < 4; mi++)
            af[mi] = *(const short8*)(sm + swz64(wr * 64 + mi * 16 + r15, g * 16));
        #pragma unroll
        for (int ni = 0; ni < 4; ni++)
            bfr[ni] = *(const short8*)(sm + 8192 + swz64(wc * 64 + ni * 16 + r15, g * 16));
        #pragma unroll
        for (int mi = 0; mi < 4; mi++)
            #pragma unroll
            for (int ni = 0; ni < 4; ni++)
                acc[mi][ni] = __builtin_amdgcn_mfma_f32_16x16x32_bf16(af[mi], bfr[ni], acc[mi][ni], 0, 0, 0);
        __syncthreads();
    }
    #pragma unroll
    for (int mi = 0; mi < 4; mi++) {
        #pragma unroll
        for (int ni = 0; ni < 4; ni++) {
            int col = n0 + wc * 64 + ni * 16 + r15;
            float bv = bias ? bias[col] : 0.f;
            #pragma unroll
            for (int r = 0; r < 4; r++) {
                int grow = m0 + wr * 64 + mi * 16 + g * 4 + r;
                if (grow < M)
                    C[(size_t)grow * N + col] = acc[mi][ni][r] + bv;
            }
        }
    }
}

// ---------------- RMS norm + RoPE + concat + bf16 cast (Q/K paths) ----------------
// one wave per (s, h); lane holds elems 2l, 2l+1 of the 128-dim head row.
template<int ISQ>
__global__ __launch_bounds__(256)
void rmsrope(const float* __restrict__ Pimg, const float* __restrict__ Ptxt,
             const float* __restrict__ wimg, const float* __restrict__ wtxt,
             const float* __restrict__ cosb, const float* __restrict__ sinb,
             unsigned short* __restrict__ dst, unsigned short* __restrict__ ipq)
{
    int wg = blockIdx.x * 4 + (threadIdx.x >> 6);
    int lane = threadIdx.x & 63;
    int s = wg / H;
    int h = wg - s * H;
    const float* src = (s < S_TXT) ? (Ptxt + (size_t)s * DMODEL)
                                   : (Pimg + (size_t)(s - S_TXT) * DMODEL);
    const float* w = (s < S_TXT) ? wtxt : wimg;
    float2 x = *(const float2*)(src + h * HD + lane * 2);
    float ss = x.x * x.x + x.y * x.y;
    #pragma unroll
    for (int off = 1; off < 64; off <<= 1) ss += __shfl_xor(ss, off);
    float rr = rsqrtf(ss * (1.f / HD) + 1e-6f);
    float xn0 = x.x * rr * w[lane * 2];
    float xn1 = x.y * rr * w[lane * 2 + 1];
    if (ISQ && s >= S_TXT) {
        *(unsigned*)(ipq + (size_t)h * S_IMG * HD + (size_t)(s - S_TXT) * HD + lane * 2) = pk2(xn0, xn1);
    }
    float c0 = cosb[s * HD + lane * 2], c1 = cosb[s * HD + lane * 2 + 1];
    float sn0 = sinb[s * HD + lane * 2], sn1 = sinb[s * HD + lane * 2 + 1];
    float o0 = xn0 * c0 - xn1 * sn0;
    float o1 = xn1 * c1 + xn0 * sn1;
    *(unsigned*)(dst + (size_t)h * S_ALL * HD + (size_t)s * HD + lane * 2) = pk2(o0, o1);
}

// ---------------- V concat + transpose to [H][HD][Stot] bf16 ----------------
__global__ __launch_bounds__(256)
void vtrans(const float* __restrict__ Vimg, const float* __restrict__ Vtxt,
            unsigned short* __restrict__ vt, int Stot)
{
    __shared__ float lv[64 * 129];  // pad 129 (odd) -> transpose reads ~2-way
    int h = blockIdx.y;
    int s0 = blockIdx.x * 64;
    const float* src = (s0 < S_TXT) ? (Vtxt + (size_t)s0 * DMODEL)
                                    : (Vimg + (size_t)(s0 - S_TXT) * DMODEL);
    int tid = threadIdx.x;
    #pragma unroll
    for (int i = 0; i < 8; i++) {
        int slot = tid + 256 * i;
        int row = slot >> 5, c4 = slot & 31;
        float4 v = *(const float4*)(src + (size_t)row * DMODEL + h * HD + c4 * 4);
        float* p = lv + row * 129 + c4 * 4;
        p[0] = v.x; p[1] = v.y; p[2] = v.z; p[3] = v.w;
    }
    __syncthreads();
    #pragma unroll
    for (int i = 0; i < 4; i++) {
        int slot = tid + 256 * i;
        int d = slot >> 3, c8 = slot & 7;
        unsigned q0 = pk2(lv[(c8 * 8 + 0) * 129 + d], lv[(c8 * 8 + 1) * 129 + d]);
        unsigned q1 = pk2(lv[(c8 * 8 + 2) * 129 + d], lv[(c8 * 8 + 3) * 129 + d]);
        unsigned q2 = pk2(lv[(c8 * 8 + 4) * 129 + d], lv[(c8 * 8 + 5) * 129 + d]);
        unsigned q3 = pk2(lv[(c8 * 8 + 6) * 129 + d], lv[(c8 * 8 + 7) * 129 + d]);
        int4 o = {(int)q0, (int)q1, (int)q2, (int)q3};
        *(int4*)(vt + (size_t)(h * HD + d) * Stot + s0 + c8 * 8) = o;
    }
}

// ---------------- cast [N_IP][DMODEL] f32 -> [H][N_IP][HD] bf16 ----------------
__global__ __launch_bounds__(256)
void cast_heads(const float* __restrict__ in, unsigned short* __restrict__ out)
{
    int idx = blockIdx.x * 256 + threadIdx.x;  // over N_IP*DMODEL/2
    int s = idx / (DMODEL / 2);
    int rem = idx - s * (DMODEL / 2);
    int h = rem / (HD / 2);
    int d2 = rem - h * (HD / 2);
    float2 v = *(const float2*)(in + (size_t)s * DMODEL + h * HD + d2 * 2);
    *(unsigned*)(out + (size_t)h * N_IP * HD + s * HD + d2 * 2) = pk2(v.x, v.y);
}

// ---------------- Flash attention ----------------
// block = 4 waves, 64 q-rows (16/wave), KV tile 64.
// K lds [64][128] bf16 (swzK), Vt lds [128][64] bf16 (swzV), P per-wave [16][64] (swzV).
__device__ inline int swzK_(int row, int colb) { return row * 256 + (colb ^ ((row & 7) << 4)); }
__device__ inline int swzV_(int row, int colb) { return row * 128 + (colb ^ ((row & 7) << 4)); }

template<int MODE>  // 0 = IP (write f32), 1 = main (add ip, write bf16)
__global__ __launch_bounds__(256)
void flash(const unsigned short* __restrict__ Q, const unsigned short* __restrict__ Kb,
           const unsigned short* __restrict__ Vt, const float* __restrict__ ipb,
           void* __restrict__ Out, int Sq, int Skv)
{
    __shared__ char sm[40960];
    const int h = blockIdx.y;
    const int q0 = blockIdx.x * 64;
    const int tid = threadIdx.x, wid = tid >> 6, lane = tid & 63;
    const int r15 = lane & 15, g = lane >> 4;

    const unsigned short* Qh = Q + ((size_t)h * Sq + q0 + wid * 16 + r15) * HD;
    short8 qf[4];
    #pragma unroll
    for (int ks = 0; ks < 4; ks++)
        qf[ks] = *(const short8*)(Qh + ks * 32 + g * 8);

    float m[4], lsum[4];
    #pragma unroll
    for (int i = 0; i < 4; i++) { m[i] = -3.0e38f; lsum[i] = 0.f; }
    f32x4 o[8];
    #pragma unroll
    for (int n = 0; n < 8; n++) o[n] = {0.f, 0.f, 0.f, 0.f};

    const unsigned short* Kh = Kb + (size_t)h * Skv * HD;
    const unsigned short* Vth = Vt + (size_t)h * HD * Skv;
    char* Psm = sm + 32768 + wid * 2048;

    for (int kv0 = 0; kv0 < Skv; kv0 += 64) {
        #pragma unroll
        for (int i = 0; i < 4; i++) {
            int slot = tid + 256 * i;
            int row = slot >> 4, c8 = slot & 15;
            *(int4*)(sm + swzK_(row, c8 * 16)) =
                *(const int4*)(Kh + (size_t)(kv0 + row) * HD + c8 * 8);
            int row2 = slot >> 3, c82 = slot & 7;
            *(int4*)(sm + 16384 + swzV_(row2, c82 * 16)) =
                *(const int4*)(Vth + (size_t)row2 * Skv + kv0 + c82 * 8);
        }
        __syncthreads();
        f32x4 st[4];
        #pragma unroll
        for (int t = 0; t < 4; t++) {
            st[t] = {0.f, 0.f, 0.f, 0.f};
            #pragma unroll
            for (int ks = 0; ks < 4; ks++) {
                short8 kb = *(const short8*)(sm + swzK_(t * 16 + r15, ks * 64 + g * 16));
                st[t] = __builtin_amdgcn_mfma_f32_16x16x32_bf16(qf[ks], kb, st[t], 0, 0, 0);
            }
        }
        #pragma unroll
        for (int t = 0; t < 4; t++)
            #pragma unroll
            for (int i = 0; i < 4; i++) st[t][i] *= SM_SCALE;
        #pragma unroll
        for (int i = 0; i < 4; i++) {
            float tm = fmaxf(fmaxf(st[0][i], st[1][i]), fmaxf(st[2][i], st[3][i]));
            tm = fmaxf(tm, __shfl_xor(tm, 1));
            tm = fmaxf(tm, __shfl_xor(tm, 2));
            tm = fmaxf(tm, __shfl_xor(tm, 4));
            tm = fmaxf(tm, __shfl_xor(tm, 8));
            float mn = fmaxf(m[i], tm);
            float sc = __expf(m[i] - mn);
            m[i] = mn;
            lsum[i] *= sc;
            #pragma unroll
            for (int n = 0; n < 8; n++) o[n][i] *= sc;
            float r0 = 0.f;
            #pragma unroll
            for (int t = 0; t < 4; t++) {
                float p = __expf(st[t][i] - mn);
                st[t][i] = p;
                r0 += p;
            }
            r0 += __shfl_xor(r0, 1); r0 += __shfl_xor(r0, 2);
            r0 += __shfl_xor(r0, 4); r0 += __shfl_xor(r0, 8);
            lsum[i] += r0;
        }
        #pragma unroll
        for (int t = 0; t < 4; t++)
            #pragma unroll
            for (int i = 0; i < 4; i++) {
                int row = g * 4 + i, col = t * 16 + r15;
                *(unsigned short*)(Psm + swzV_(row, col * 2)) = f2bf(st[t][i]);
            }
        asm volatile("s_waitcnt lgkmcnt(0)" ::: "memory");
        #pragma unroll
        for (int ks2 = 0; ks2 < 2; ks2++) {
            short8 pa = *(const short8*)(Psm + swzV_(r15, ks2 * 64 + g * 16));
            #pragma unroll
            for (int n = 0; n < 8; n++) {
                short8 vb = *(const short8*)(sm + 16384 + swzV_(n * 16 + r15, ks2 * 64 + g * 16));
                o[n] = __builtin_amdgcn_mfma_f32_16x16x32_bf16(pa, vb, o[n], 0, 0, 0);
            }
        }
        __syncthreads();
    }
    #pragma unroll
    for (int i = 0; i < 4; i++) lsum[i] = 1.f / lsum[i];
    #pragma unroll
    for (int n = 0; n < 8; n++)
        #pragma unroll
        for (int i = 0; i < 4; i++) {
            int qrow = q0 + wid * 16 + g * 4 + i;
            int col = h * HD + n * 16 + r15;
            float val = o[n][i] * lsum[i];
            if (MODE == 0) {
                ((float*)Out)[(size_t)qrow * DMODEL + col] = val;
            } else {
                if (qrow >= S_TXT) val += ipb[(size_t)(qrow - S_TXT) * DMODEL + col];
                ((unsigned short*)Out)[(size_t)qrow * DMODEL + col] = f2bf(val);
            }
        }
}

// ---------------- launch ----------------
extern "C" void kernel_launch(void* const* d_in, const int* in_sizes, int n_in,
                              void* d_out, int out_size, void* d_ws, size_t ws_size,
                              hipStream_t stream)
{
    const float* hs   = (const float*)d_in[0];
    const float* enc  = (const float*)d_in[1];
    const float* iemb = (const float*)d_in[2];
    const float* cosb = (const float*)d_in[3];
    const float* sinb = (const float*)d_in[4];
    const float* Wq  = (const float*)d_in[5];  const float* bq  = (const float*)d_in[6];
    const float* Wk  = (const float*)d_in[7];  const float* bk  = (const float*)d_in[8];
    const float* Wv  = (const float*)d_in[9];  const float* bv  = (const float*)d_in[10];
    const float* Waq = (const float*)d_in[11]; const float* baq = (const float*)d_in[12];
    const float* Wak = (const float*)d_in[13]; const float* bak = (const float*)d_in[14];
    const float* Wav = (const float*)d_in[15]; const float* bav = (const float*)d_in[16];
    const float* Wo  = (const float*)d_in[17]; const float* bo  = (const float*)d_in[18];
    const float* Wao = (const float*)d_in[19]; const float* bao = (const float*)d_in[20];
    const float* nq  = (const float*)d_in[21]; const float* nk  = (const float*)d_in[22];
    const float* naq = (const float*)d_in[23]; const float* nak = (const float*)d_in[24];
    const float* Wkip = (const float*)d_in[25]; const float* Wvip = (const float*)d_in[26];

    char* ws = (char*)d_ws;
    size_t off = 0;
    auto alloc = [&](size_t b) { char* p = ws + off; off += (b + 255) & ~(size_t)255; return p; };
    float* bufA  = (float*)alloc((size_t)S_IMG * DMODEL * 4);
    float* bufB  = (float*)alloc((size_t)S_TXT * DMODEL * 4);
    float* ipkf  = (float*)alloc((size_t)N_IP * DMODEL * 4);
    float* ipvf  = (float*)alloc((size_t)N_IP * DMODEL * 4);
    unsigned short* qb    = (unsigned short*)alloc((size_t)H * S_ALL * HD * 2);
    unsigned short* kbf   = (unsigned short*)alloc((size_t)H * S_ALL * HD * 2);
    unsigned short* vtb   = (unsigned short*)alloc((size_t)H * HD * S_ALL * 2);
    unsigned short* ipqb  = (unsigned short*)alloc((size_t)H * S_IMG * HD * 2);
    unsigned short* ipkb  = (unsigned short*)alloc((size_t)H * N_IP * HD * 2);
    unsigned short* ipvtb = (unsigned short*)alloc((size_t)H * HD * N_IP * 2);
    float* ipbuf = (float*)alloc((size_t)S_IMG * DMODEL * 4);
    unsigned short* attnb = (unsigned short*)alloc((size_t)S_ALL * DMODEL * 2);
    (void)ws_size; (void)in_sizes; (void)n_in; (void)out_size;

    dim3 blk(256);
    // Q path
    gemm_bt<0><<<dim3(16, 24), blk, 0, stream>>>(hs, Wq, bq, bufA, S_IMG, DMODEL, DMODEL);
    gemm_bt<0><<<dim3(4, 24),  blk, 0, stream>>>(enc, Waq, baq, bufB, S_TXT, DMODEL, DMODEL);
    rmsrope<1><<<dim3(15360), blk, 0, stream>>>(bufA, bufB, nq, naq, cosb, sinb, qb, ipqb);
    // K path
    gemm_bt<0><<<dim3(16, 24), blk, 0, stream>>>(hs, Wk, bk, bufA, S_IMG, DMODEL, DMODEL);
    gemm_bt<0><<<dim3(4, 24),  blk, 0, stream>>>(enc, Wak, bak, bufB, S_TXT, DMODEL, DMODEL);
    rmsrope<0><<<dim3(15360), blk, 0, stream>>>(bufA, bufB, nk, nak, cosb, sinb, kbf, nullptr);
    // V path
    gemm_bt<0><<<dim3(16, 24), blk, 0, stream>>>(hs, Wv, bv, bufA, S_IMG, DMODEL, DMODEL);
    gemm_bt<0><<<dim3(4, 24),  blk, 0, stream>>>(enc, Wav, bav, bufB, S_TXT, DMODEL, DMODEL);
    vtrans<<<dim3(40, 24), blk, 0, stream>>>(bufA, bufB, vtb, S_ALL);
    // IP K/V
    gemm_bt<0><<<dim3(1, 24), blk, 0, stream>>>(iemb, Wkip, nullptr, ipkf, N_IP, DMODEL, EMB);
    gemm_bt<0><<<dim3(1, 24), blk, 0, stream>>>(iemb, Wvip, nullptr, ipvf, N_IP, DMODEL, EMB);
    cast_heads<<<dim3(384), blk, 0, stream>>>(ipkf, ipkb);
    vtrans<<<dim3(1, 24), blk, 0, stream>>>(ipvf, ipvf, ipvtb, N_IP);
    // IP attention (pre-rope normed q), then main attention fusing the add
    flash<0><<<dim3(32, 24), blk, 0, stream>>>(ipqb, ipkb, ipvtb, nullptr, ipbuf, S_IMG, N_IP);
    flash<1><<<dim3(40, 24), blk, 0, stream>>>(qb, kbf, vtb, ipbuf, attnb, S_ALL, S_ALL);
    // output projections
    float* dout = (float*)d_out;
    gemm_bt<1><<<dim3(16, 24), blk, 0, stream>>>(attnb + (size_t)S_TXT * DMODEL, Wo, bo, dout, S_IMG, DMODEL, DMODEL);
    gemm_bt<1><<<dim3(4, 24),  blk, 0, stream>>>(attnb, Wao, bao, dout + (size_t)S_IMG * DMODEL, S_TXT, DMODEL, DMODEL);
}

// Round 2
// 913.512 us; speedup vs baseline: 2.6358x; 2.6358x over previous
//
#include <hip/hip_runtime.h>
#include <hip/hip_bf16.h>

#define H 24
#define HD 128
#define DMODEL 3072
#define S_IMG 2048
#define S_TXT 512
#define S_ALL 2560
#define EMB 4096
#define N_IP 64
#define SM_SCALE 0.08838834764831845f  // 1/sqrt(128)

typedef __attribute__((ext_vector_type(8))) short short8;
typedef __attribute__((ext_vector_type(4))) float f32x4;

__device__ inline unsigned short f2bf(float f) {
    unsigned u = __builtin_bit_cast(unsigned, f);
    return (unsigned short)((u + 0x7fffu + ((u >> 16) & 1u)) >> 16);
}
__device__ inline unsigned pk2(float a, float b) {
    return (unsigned)f2bf(a) | ((unsigned)f2bf(b) << 16);
}

__device__ inline void gload16(const void* g, void* l) {
    __builtin_amdgcn_global_load_lds(
        (const __attribute__((address_space(1))) unsigned int*)g,
        (__attribute__((address_space(3))) unsigned int*)(unsigned int)(unsigned long long)l,
        16, 0, 0);
}

// ---------------- f32 -> bf16 cast (grid-stride, 8 elems/thread, zero-pad past n8) ----------------
__global__ __launch_bounds__(256)
void castk(const float* __restrict__ in, unsigned short* __restrict__ out, int n8, int ntot8)
{
    for (int i = blockIdx.x * 256 + threadIdx.x; i < ntot8; i += gridDim.x * 256) {
        int4 o;
        if (i < n8) {
            const float4* p = (const float4*)(in + (size_t)i * 8);
            float4 a = p[0], b = p[1];
            o.x = pk2(a.x, a.y); o.y = pk2(a.z, a.w);
            o.z = pk2(b.x, b.y); o.w = pk2(b.z, b.w);
        } else {
            o.x = 0; o.y = 0; o.z = 0; o.w = 0;
        }
        *(int4*)(out + (size_t)i * 8) = o;
    }
}

__global__ __launch_bounds__(256)
void bcat3(const float* __restrict__ b0, const float* __restrict__ b1,
           const float* __restrict__ b2, float* __restrict__ dst)
{
    int i = blockIdx.x * 256 + threadIdx.x;  // 9216
    float v = (i < DMODEL) ? b0[i] : ((i < 2 * DMODEL) ? b1[i - DMODEL] : b2[i - 2 * DMODEL]);
    dst[i] = v;
}

// ---------------- GEMM (m97 structure): C[M,N] = A[M,K]bf16 @ B[N,K]bf16^T + bias ----------------
// 128x128 tile, BK=64, 4 waves (2x2, 64x64 each). global_load_lds width 16 into
// linear LDS [128][64]bf16; XOR swizzle via pre-swizzled global source (rule #21).
// Requires: M%128==0, K%64==0, grid.x = (M/128)*(N/128) with %8==0 (XCD swizzle).
__global__ __launch_bounds__(256)
void gemm16(const unsigned short* __restrict__ A, const unsigned short* __restrict__ B,
            const float* __restrict__ bias, float* __restrict__ C,
            int M, int N, int K, int nbn)
{
    __shared__ unsigned short sm[2 * 8192];  // A tile 16KB @0, B tile 16KB @8192 elems
    const int tid = threadIdx.x, lane = tid & 63, wid = tid >> 6;
    const int wr = wid >> 1, wc = wid & 1;
    const int r15 = lane & 15, g = lane >> 4;

    // XCD-aware block swizzle (grid %8 == 0 guaranteed by launch)
    int nwg = gridDim.x;
    int flat = blockIdx.x;
    int swz = (flat & 7) * (nwg >> 3) + (flat >> 3);
    int mb = swz / nbn, nb = swz - mb * nbn;
    const int m0 = mb * 128, n0 = nb * 128;

    // staging geometry: each wave owns 4 chunks of 8 rows x 64 elems (1KB LDS each)
    const int lr = lane >> 3;          // row within chunk, == row&7
    const int lc = lane & 7;           // 16B slot within row
    const int gcol = ((lc * 16) ^ (lr << 4)) >> 1;  // inverse-swizzled source element col

    const unsigned short* Ab = A + (size_t)(m0 + wid * 32 + lr) * K + gcol;
    const unsigned short* Bb = B + (size_t)(n0 + wid * 32 + lr) * K + gcol;
    char* smc = (char*)sm;

    f32x4 acc[4][4];
    #pragma unroll
    for (int i = 0; i < 4; i++)
        #pragma unroll
        for (int j = 0; j < 4; j++)
            acc[i][j] = {0.f, 0.f, 0.f, 0.f};

    for (int k0 = 0; k0 < K; k0 += 64) {
        #pragma unroll
        for (int cc = 0; cc < 4; cc++) {
            gload16(Ab + (size_t)cc * 8 * K + k0, smc + (wid * 32 + cc * 8) * 128);
            gload16(Bb + (size_t)cc * 8 * K + k0, smc + 16384 + (wid * 32 + cc * 8) * 128);
        }
        __syncthreads();
        #pragma unroll
        for (int ks = 0; ks < 2; ks++) {
            short8 af[4], bf[4];
            #pragma unroll
            for (int mi = 0; mi < 4; mi++) {
                int row = wr * 64 + mi * 16 + r15;
                af[mi] = *(const short8*)(smc + row * 128 + ((ks * 64 + g * 16) ^ ((row & 7) << 4)));
            }
            #pragma unroll
            for (int ni = 0; ni < 4; ni++) {
                int row = wc * 64 + ni * 16 + r15;
                bf[ni] = *(const short8*)(smc + 16384 + row * 128 + ((ks * 64 + g * 16) ^ ((row & 7) << 4)));
            }
            #pragma unroll
            for (int mi = 0; mi < 4; mi++)
                #pragma unroll
                for (int ni = 0; ni < 4; ni++)
                    acc[mi][ni] = __builtin_amdgcn_mfma_f32_16x16x32_bf16(af[mi], bf[ni], acc[mi][ni], 0, 0, 0);
        }
        __syncthreads();
    }
    #pragma unroll
    for (int mi = 0; mi < 4; mi++) {
        #pragma unroll
        for (int ni = 0; ni < 4; ni++) {
            int col = n0 + wc * 64 + ni * 16 + r15;
            float bv = bias ? bias[col] : 0.f;
            #pragma unroll
            for (int r = 0; r < 4; r++) {
                int grow = m0 + wr * 64 + mi * 16 + g * 4 + r;
                C[(size_t)grow * N + col] = acc[mi][ni][r] + bv;
            }
        }
    }
}

// ---------------- RMS norm + RoPE + concat + bf16 cast (Q/K paths) ----------------
template<int ISQ>
__global__ __launch_bounds__(256)
void rmsrope(const float* __restrict__ Pimg, const float* __restrict__ Ptxt,
             int stride, int colofs,
             const float* __restrict__ wimg, const float* __restrict__ wtxt,
             const float* __restrict__ cosb, const float* __restrict__ sinb,
             unsigned short* __restrict__ dst, unsigned short* __restrict__ ipq)
{
    int wg = blockIdx.x * 4 + (threadIdx.x >> 6);
    int lane = threadIdx.x & 63;
    int s = wg / H;
    int h = wg - s * H;
    const float* src = (s < S_TXT) ? (Ptxt + (size_t)s * stride)
                                   : (Pimg + (size_t)(s - S_TXT) * stride);
    src += colofs;
    const float* w = (s < S_TXT) ? wtxt : wimg;
    float2 x = *(const float2*)(src + h * HD + lane * 2);
    float ss = x.x * x.x + x.y * x.y;
    #pragma unroll
    for (int off = 1; off < 64; off <<= 1) ss += __shfl_xor(ss, off);
    float rr = rsqrtf(ss * (1.f / HD) + 1e-6f);
    float xn0 = x.x * rr * w[lane * 2];
    float xn1 = x.y * rr * w[lane * 2 + 1];
    if (ISQ && s >= S_TXT) {
        *(unsigned*)(ipq + (size_t)h * S_IMG * HD + (size_t)(s - S_TXT) * HD + lane * 2) = pk2(xn0, xn1);
    }
    float c0 = cosb[s * HD + lane * 2], c1 = cosb[s * HD + lane * 2 + 1];
    float sn0 = sinb[s * HD + lane * 2], sn1 = sinb[s * HD + lane * 2 + 1];
    float o0 = xn0 * c0 - xn1 * sn0;
    float o1 = xn1 * c1 + xn0 * sn1;
    *(unsigned*)(dst + (size_t)h * S_ALL * HD + (size_t)s * HD + lane * 2) = pk2(o0, o1);
}

// ---------------- V concat + transpose to [H][HD][Stot] bf16 ----------------
__global__ __launch_bounds__(256)
void vtrans(const float* __restrict__ Vimg, const float* __restrict__ Vtxt,
            int stride, int colofs, unsigned short* __restrict__ vt, int Stot)
{
    __shared__ float lv[64 * 129];
    int h = blockIdx.y;
    int s0 = blockIdx.x * 64;
    const float* src = (s0 < S_TXT) ? (Vtxt + (size_t)s0 * stride)
                                    : (Vimg + (size_t)(s0 - S_TXT) * stride);
    src += colofs;
    int tid = threadIdx.x;
    #pragma unroll
    for (int i = 0; i < 8; i++) {
        int slot = tid + 256 * i;
        int row = slot >> 5, c4 = slot & 31;
        float4 v = *(const float4*)(src + (size_t)row * stride + h * HD + c4 * 4);
        float* p = lv + row * 129 + c4 * 4;
        p[0] = v.x; p[1] = v.y; p[2] = v.z; p[3] = v.w;
    }
    __syncthreads();
    #pragma unroll
    for (int i = 0; i < 4; i++) {
        int slot = tid + 256 * i;
        int d = slot >> 3, c8 = slot & 7;
        unsigned q0 = pk2(lv[(c8 * 8 + 0) * 129 + d], lv[(c8 * 8 + 1) * 129 + d]);
        unsigned q1 = pk2(lv[(c8 * 8 + 2) * 129 + d], lv[(c8 * 8 + 3) * 129 + d]);
        unsigned q2 = pk2(lv[(c8 * 8 + 4) * 129 + d], lv[(c8 * 8 + 5) * 129 + d]);
        unsigned q3 = pk2(lv[(c8 * 8 + 6) * 129 + d], lv[(c8 * 8 + 7) * 129 + d]);
        int4 o = {(int)q0, (int)q1, (int)q2, (int)q3};
        *(int4*)(vt + (size_t)(h * HD + d) * Stot + s0 + c8 * 8) = o;
    }
}

// ---------------- cast [N][stride] f32 (col block) -> [H][N][HD] bf16 ----------------
__global__ __launch_bounds__(256)
void cast_heads(const float* __restrict__ in, int stride, int colofs,
                unsigned short* __restrict__ out)
{
    int idx = blockIdx.x * 256 + threadIdx.x;  // over N_IP*DMODEL/2
    int s = idx / (DMODEL / 2);
    int rem = idx - s * (DMODEL / 2);
    int h = rem / (HD / 2);
    int d2 = rem - h * (HD / 2);
    float2 v = *(const float2*)(in + (size_t)s * stride + colofs + h * HD + d2 * 2);
    *(unsigned*)(out + (size_t)h * N_IP * HD + s * HD + d2 * 2) = pk2(v.x, v.y);
}

// ---------------- Flash attention ----------------
__device__ inline int swzK_(int row, int colb) { return row * 256 + (colb ^ ((row & 7) << 4)); }
__device__ inline int swzV_(int row, int colb) { return row * 128 + (colb ^ ((row & 7) << 4)); }

template<int MODE>  // 0 = IP (write f32), 1 = main (add ip, write bf16)
__global__ __launch_bounds__(256)
void flash(const unsigned short* __restrict__ Q, const unsigned short* __restrict__ Kb,
           const unsigned short* __restrict__ Vt, const float* __restrict__ ipb,
           void* __restrict__ Out, int Sq, int Skv)
{
    __shared__ char sm[40960];
    const int h = blockIdx.y;
    const int q0 = blockIdx.x * 64;
    const int tid = threadIdx.x, wid = tid >> 6, lane = tid & 63;
    const int r15 = lane & 15, g = lane >> 4;

    const unsigned short* Qh = Q + ((size_t)h * Sq + q0 + wid * 16 + r15) * HD;
    short8 qf[4];
    #pragma unroll
    for (int ks = 0; ks < 4; ks++)
        qf[ks] = *(const short8*)(Qh + ks * 32 + g * 8);

    float m[4], lsum[4];
    #pragma unroll
    for (int i = 0; i < 4; i++) { m[i] = -3.0e38f; lsum[i] = 0.f; }
    f32x4 o[8];
    #pragma unroll
    for (int n = 0; n < 8; n++) o[n] = {0.f, 0.f, 0.f, 0.f};

    const unsigned short* Kh = Kb + (size_t)h * Skv * HD;
    const unsigned short* Vth = Vt + (size_t)h * HD * Skv;
    char* Psm = sm + 32768 + wid * 2048;

    for (int kv0 = 0; kv0 < Skv; kv0 += 64) {
        #pragma unroll
        for (int i = 0; i < 4; i++) {
            int slot = tid + 256 * i;
            int row = slot >> 4, c8 = slot & 15;
            *(int4*)(sm + swzK_(row, c8 * 16)) =
                *(const int4*)(Kh + (size_t)(kv0 + row) * HD + c8 * 8);
            int row2 = slot >> 3, c82 = slot & 7;
            *(int4*)(sm + 16384 + swzV_(row2, c82 * 16)) =
                *(const int4*)(Vth + (size_t)row2 * Skv + kv0 + c82 * 8);
        }
        __syncthreads();
        f32x4 st[4];
        #pragma unroll
        for (int t = 0; t < 4; t++) {
            st[t] = {0.f, 0.f, 0.f, 0.f};
            #pragma unroll
            for (int ks = 0; ks < 4; ks++) {
                short8 kb = *(const short8*)(sm + swzK_(t * 16 + r15, ks * 64 + g * 16));
                st[t] = __builtin_amdgcn_mfma_f32_16x16x32_bf16(qf[ks], kb, st[t], 0, 0, 0);
            }
        }
        #pragma unroll
        for (int t = 0; t < 4; t++)
            #pragma unroll
            for (int i = 0; i < 4; i++) st[t][i] *= SM_SCALE;
        #pragma unroll
        for (int i = 0; i < 4; i++) {
            float tm = fmaxf(fmaxf(st[0][i], st[1][i]), fmaxf(st[2][i], st[3][i]));
            tm = fmaxf(tm, __shfl_xor(tm, 1));
            tm = fmaxf(tm, __shfl_xor(tm, 2));
            tm = fmaxf(tm, __shfl_xor(tm, 4));
            tm = fmaxf(tm, __shfl_xor(tm, 8));
            float mn = fmaxf(m[i], tm);
            float sc = __expf(m[i] - mn);
            m[i] = mn;
            lsum[i] *= sc;
            #pragma unroll
            for (int n = 0; n < 8; n++) o[n][i] *= sc;
            float r0 = 0.f;
            #pragma unroll
            for (int t = 0; t < 4; t++) {
                float p = __expf(st[t][i] - mn);
                st[t][i] = p;
                r0 += p;
            }
            r0 += __shfl_xor(r0, 1); r0 += __shfl_xor(r0, 2);
            r0 += __shfl_xor(r0, 4); r0 += __shfl_xor(r0, 8);
            lsum[i] += r0;
        }
        #pragma unroll
        for (int t = 0; t < 4; t++)
            #pragma unroll
            for (int i = 0; i < 4; i++) {
                int row = g * 4 + i, col = t * 16 + r15;
                *(unsigned short*)(Psm + swzV_(row, col * 2)) = f2bf(st[t][i]);
            }
        asm volatile("s_waitcnt lgkmcnt(0)" ::: "memory");
        #pragma unroll
        for (int ks2 = 0; ks2 < 2; ks2++) {
            short8 pa = *(const short8*)(Psm + swzV_(r15, ks2 * 64 + g * 16));
            #pragma unroll
            for (int n = 0; n < 8; n++) {
                short8 vb = *(const short8*)(sm + 16384 + swzV_(n * 16 + r15, ks2 * 64 + g * 16));
                o[n] = __builtin_amdgcn_mfma_f32_16x16x32_bf16(pa, vb, o[n], 0, 0, 0);
            }
        }
        __syncthreads();
    }
    #pragma unroll
    for (int i = 0; i < 4; i++) lsum[i] = 1.f / lsum[i];
    #pragma unroll
    for (int n = 0; n < 8; n++)
        #pragma unroll
        for (int i = 0; i < 4; i++) {
            int qrow = q0 + wid * 16 + g * 4 + i;
            int col = h * HD + n * 16 + r15;
            float val = o[n][i] * lsum[i];
            if (MODE == 0) {
                ((float*)Out)[(size_t)qrow * DMODEL + col] = val;
            } else {
                if (qrow >= S_TXT) val += ipb[(size_t)(qrow - S_TXT) * DMODEL + col];
                ((unsigned short*)Out)[(size_t)qrow * DMODEL + col] = f2bf(val);
            }
        }
}

// ---------------- launch ----------------
extern "C" void kernel_launch(void* const* d_in, const int* in_sizes, int n_in,
                              void* d_out, int out_size, void* d_ws, size_t ws_size,
                              hipStream_t stream)
{
    const float* hs   = (const float*)d_in[0];
    const float* enc  = (const float*)d_in[1];
    const float* iemb = (const float*)d_in[2];
    const float* cosb = (const float*)d_in[3];
    const float* sinb = (const float*)d_in[4];
    const float* Wq  = (const float*)d_in[5];  const float* bq  = (const float*)d_in[6];
    const float* Wk  = (const float*)d_in[7];  const float* bk  = (const float*)d_in[8];
    const float* Wv  = (const float*)d_in[9];  const float* bv  = (const float*)d_in[10];
    const float* Waq = (const float*)d_in[11]; const float* baq = (const float*)d_in[12];
    const float* Wak = (const float*)d_in[13]; const float* bak = (const float*)d_in[14];
    const float* Wav = (const float*)d_in[15]; const float* bav = (const float*)d_in[16];
    const float* Wo  = (const float*)d_in[17]; const float* bo  = (const float*)d_in[18];
    const float* Wao = (const float*)d_in[19]; const float* bao = (const float*)d_in[20];
    const float* nq  = (const float*)d_in[21]; const float* nk  = (const float*)d_in[22];
    const float* naq = (const float*)d_in[23]; const float* nak = (const float*)d_in[24];
    const float* Wkip = (const float*)d_in[25]; const float* Wvip = (const float*)d_in[26];
    (void)in_sizes; (void)n_in; (void)out_size; (void)ws_size;

    char* ws = (char*)d_ws;
    size_t off = 0;
    auto alloc = [&](size_t b) { char* p = ws + off; off += (b + 255) & ~(size_t)255; return p; };
    // f32 GEMM outputs
    float* qkv_img = (float*)alloc((size_t)S_IMG * 3 * DMODEL * 4);   // 75.5 MB (aliased by ipbuf)
    float* qkv_txt = (float*)alloc((size_t)S_TXT * 3 * DMODEL * 4);   // 18.9 MB (aliased by attnb)
    float* ipkv    = (float*)alloc((size_t)128 * 2 * DMODEL * 4);
    // bf16 inputs
    unsigned short* hs_bf   = (unsigned short*)alloc((size_t)S_IMG * DMODEL * 2);
    unsigned short* enc_bf  = (unsigned short*)alloc((size_t)S_TXT * DMODEL * 2);
    unsigned short* iemb_bf = (unsigned short*)alloc((size_t)128 * EMB * 2);
    // bf16 weights (concatenated)
    unsigned short* Wqkv  = (unsigned short*)alloc((size_t)3 * DMODEL * DMODEL * 2);
    unsigned short* Waqkv = (unsigned short*)alloc((size_t)3 * DMODEL * DMODEL * 2);
    unsigned short* Wo_b  = (unsigned short*)alloc((size_t)DMODEL * DMODEL * 2);
    unsigned short* Wao_b = (unsigned short*)alloc((size_t)DMODEL * DMODEL * 2);
    unsigned short* Wip   = (unsigned short*)alloc((size_t)2 * DMODEL * EMB * 2);
    float* bqkv  = (float*)alloc(3 * DMODEL * 4);
    float* baqkv = (float*)alloc(3 * DMODEL * 4);
    // attention operands
    unsigned short* qb    = (unsigned short*)alloc((size_t)H * S_ALL * HD * 2);
    unsigned short* kbf   = (unsigned short*)alloc((size_t)H * S_ALL * HD * 2);
    unsigned short* vtb   = (unsigned short*)alloc((size_t)H * HD * S_ALL * 2);
    unsigned short* ipqb  = (unsigned short*)alloc((size_t)H * S_IMG * HD * 2);
    unsigned short* ipkb  = (unsigned short*)alloc((size_t)H * N_IP * HD * 2);
    unsigned short* ipvtb = (unsigned short*)alloc((size_t)H * HD * N_IP * 2);
    // aliases (consumers of qkv_img/txt all run before these are written)
    float* ipbuf = qkv_img;
    unsigned short* attnb = (unsigned short*)qkv_txt;

    dim3 blk(256);
    const int D2 = DMODEL * DMODEL / 8;
    // casts
    castk<<<1024, blk, 0, stream>>>(hs,   hs_bf,   S_IMG * DMODEL / 8, S_IMG * DMODEL / 8);
    castk<<<256,  blk, 0, stream>>>(enc,  enc_bf,  S_TXT * DMODEL / 8, S_TXT * DMODEL / 8);
    castk<<<128,  blk, 0, stream>>>(iemb, iemb_bf, N_IP * EMB / 8, 128 * EMB / 8);
    castk<<<1024, blk, 0, stream>>>(Wq,  Wqkv,              D2, D2);
    castk<<<1024, blk, 0, stream>>>(Wk,  Wqkv + (size_t)DMODEL * DMODEL,     D2, D2);
    castk<<<1024, blk, 0, stream>>>(Wv,  Wqkv + (size_t)2 * DMODEL * DMODEL, D2, D2);
    castk<<<1024, blk, 0, stream>>>(Waq, Waqkv,             D2, D2);
    castk<<<1024, blk, 0, stream>>>(Wak, Waqkv + (size_t)DMODEL * DMODEL,     D2, D2);
    castk<<<1024, blk, 0, stream>>>(Wav, Waqkv + (size_t)2 * DMODEL * DMODEL, D2, D2);
    castk<<<1024, blk, 0, stream>>>(Wo,  Wo_b,  D2, D2);
    castk<<<1024, blk, 0, stream>>>(Wao, Wao_b, D2, D2);
    castk<<<1024, blk, 0, stream>>>(Wkip, Wip,                           DMODEL * EMB / 8, DMODEL * EMB / 8);
    castk<<<1024, blk, 0, stream>>>(Wvip, Wip + (size_t)DMODEL * EMB,    DMODEL * EMB / 8, DMODEL * EMB / 8);
    bcat3<<<36, blk, 0, stream>>>(bq, bk, bv, bqkv);
    bcat3<<<36, blk, 0, stream>>>(baq, bak, bav, baqkv);

    // projections (batched QKV)
    gemm16<<<dim3(16 * 72), blk, 0, stream>>>(hs_bf,  Wqkv,  bqkv,  qkv_img, S_IMG, 3 * DMODEL, DMODEL, 72);
    gemm16<<<dim3(4 * 72),  blk, 0, stream>>>(enc_bf, Waqkv, baqkv, qkv_txt, S_TXT, 3 * DMODEL, DMODEL, 72);
    gemm16<<<dim3(1 * 48),  blk, 0, stream>>>(iemb_bf, Wip, nullptr, ipkv, 128, 2 * DMODEL, EMB, 48);

    // epilogues
    rmsrope<1><<<dim3(15360), blk, 0, stream>>>(qkv_img, qkv_txt, 3 * DMODEL, 0,      nq, naq, cosb, sinb, qb, ipqb);
    rmsrope<0><<<dim3(15360), blk, 0, stream>>>(qkv_img, qkv_txt, 3 * DMODEL, DMODEL, nk, nak, cosb, sinb, kbf, nullptr);
    vtrans<<<dim3(40, 24), blk, 0, stream>>>(qkv_img, qkv_txt, 3 * DMODEL, 2 * DMODEL, vtb, S_ALL);
    cast_heads<<<dim3(384), blk, 0, stream>>>(ipkv, 2 * DMODEL, 0, ipkb);
    vtrans<<<dim3(1, 24), blk, 0, stream>>>(ipkv, ipkv, 2 * DMODEL, DMODEL, ipvtb, N_IP);

    // attention
    flash<0><<<dim3(32, 24), blk, 0, stream>>>(ipqb, ipkb, ipvtb, nullptr, ipbuf, S_IMG, N_IP);
    flash<1><<<dim3(40, 24), blk, 0, stream>>>(qb, kbf, vtb, ipbuf, attnb, S_ALL, S_ALL);

    // output projections
    float* dout = (float*)d_out;
    gemm16<<<dim3(16 * 24), blk, 0, stream>>>(attnb + (size_t)S_TXT * DMODEL, Wo_b, bo, dout, S_IMG, DMODEL, DMODEL, 24);
    gemm16<<<dim3(4 * 24),  blk, 0, stream>>>(attnb, Wao_b, bao, dout + (size_t)S_IMG * DMODEL, S_TXT, DMODEL, DMODEL, 24);
}

// Round 3
// 856.442 us; speedup vs baseline: 2.8114x; 1.0666x over previous
//
#include <hip/hip_runtime.h>
#include <hip/hip_bf16.h>

#define H 24
#define HD 128
#define DMODEL 3072
#define S_IMG 2048
#define S_TXT 512
#define S_ALL 2560
#define EMB 4096
#define N_IP 64
#define SM_SCALE 0.08838834764831845f  // 1/sqrt(128)

typedef __attribute__((ext_vector_type(8))) short short8;
typedef __attribute__((ext_vector_type(4))) float f32x4;
typedef __attribute__((ext_vector_type(16))) float f32x16;

__device__ inline unsigned short f2bf(float f) {
    unsigned u = __builtin_bit_cast(unsigned, f);
    return (unsigned short)((u + 0x7fffu + ((u >> 16) & 1u)) >> 16);
}
__device__ inline unsigned pk2(float a, float b) {
    return (unsigned)f2bf(a) | ((unsigned)f2bf(b) << 16);
}

__device__ inline void gload16(const void* g, void* l) {
    __builtin_amdgcn_global_load_lds(
        (const __attribute__((address_space(1))) unsigned int*)g,
        (__attribute__((address_space(3))) unsigned int*)(unsigned int)(unsigned long long)l,
        16, 0, 0);
}

// ---------------- f32 -> bf16 cast ----------------
__global__ __launch_bounds__(256)
void castk(const float* __restrict__ in, unsigned short* __restrict__ out, int n8, int ntot8)
{
    for (int i = blockIdx.x * 256 + threadIdx.x; i < ntot8; i += gridDim.x * 256) {
        int4 o;
        if (i < n8) {
            const float4* p = (const float4*)(in + (size_t)i * 8);
            float4 a = p[0], b = p[1];
            o.x = pk2(a.x, a.y); o.y = pk2(a.z, a.w);
            o.z = pk2(b.x, b.y); o.w = pk2(b.z, b.w);
        } else {
            o.x = 0; o.y = 0; o.z = 0; o.w = 0;
        }
        *(int4*)(out + (size_t)i * 8) = o;
    }
}

__global__ __launch_bounds__(256)
void bcat3(const float* __restrict__ b0, const float* __restrict__ b1,
           const float* __restrict__ b2, float* __restrict__ dst)
{
    int i = blockIdx.x * 256 + threadIdx.x;  // 9216
    float v = (i < DMODEL) ? b0[i] : ((i < 2 * DMODEL) ? b1[i - DMODEL] : b2[i - 2 * DMODEL]);
    dst[i] = v;
}

// ---------------- GEMM (m97 structure) ----------------
__global__ __launch_bounds__(256)
void gemm16(const unsigned short* __restrict__ A, const unsigned short* __restrict__ B,
            const float* __restrict__ bias, float* __restrict__ C,
            int M, int N, int K, int nbn)
{
    __shared__ unsigned short sm[2 * 8192];
    const int tid = threadIdx.x, lane = tid & 63, wid = tid >> 6;
    const int wr = wid >> 1, wc = wid & 1;
    const int r15 = lane & 15, g = lane >> 4;

    int nwg = gridDim.x;
    int flat = blockIdx.x;
    int swz = (flat & 7) * (nwg >> 3) + (flat >> 3);
    int mb = swz / nbn, nb = swz - mb * nbn;
    const int m0 = mb * 128, n0 = nb * 128;

    const int lr = lane >> 3;
    const int lc = lane & 7;
    const int gcol = ((lc * 16) ^ (lr << 4)) >> 1;

    const unsigned short* Ab = A + (size_t)(m0 + wid * 32 + lr) * K + gcol;
    const unsigned short* Bb = B + (size_t)(n0 + wid * 32 + lr) * K + gcol;
    char* smc = (char*)sm;

    f32x4 acc[4][4];
    #pragma unroll
    for (int i = 0; i < 4; i++)
        #pragma unroll
        for (int j = 0; j < 4; j++)
            acc[i][j] = {0.f, 0.f, 0.f, 0.f};

    for (int k0 = 0; k0 < K; k0 += 64) {
        #pragma unroll
        for (int cc = 0; cc < 4; cc++) {
            gload16(Ab + (size_t)cc * 8 * K + k0, smc + (wid * 32 + cc * 8) * 128);
            gload16(Bb + (size_t)cc * 8 * K + k0, smc + 16384 + (wid * 32 + cc * 8) * 128);
        }
        __syncthreads();
        #pragma unroll
        for (int ks = 0; ks < 2; ks++) {
            short8 af[4], bf[4];
            #pragma unroll
            for (int mi = 0; mi < 4; mi++) {
                int row = wr * 64 + mi * 16 + r15;
                af[mi] = *(const short8*)(smc + row * 128 + ((ks * 64 + g * 16) ^ ((row & 7) << 4)));
            }
            #pragma unroll
            for (int ni = 0; ni < 4; ni++) {
                int row = wc * 64 + ni * 16 + r15;
                bf[ni] = *(const short8*)(smc + 16384 + row * 128 + ((ks * 64 + g * 16) ^ ((row & 7) << 4)));
            }
            #pragma unroll
            for (int mi = 0; mi < 4; mi++)
                #pragma unroll
                for (int ni = 0; ni < 4; ni++)
                    acc[mi][ni] = __builtin_amdgcn_mfma_f32_16x16x32_bf16(af[mi], bf[ni], acc[mi][ni], 0, 0, 0);
        }
        __syncthreads();
    }
    #pragma unroll
    for (int mi = 0; mi < 4; mi++) {
        #pragma unroll
        for (int ni = 0; ni < 4; ni++) {
            int col = n0 + wc * 64 + ni * 16 + r15;
            float bv = bias ? bias[col] : 0.f;
            #pragma unroll
            for (int r = 0; r < 4; r++) {
                int grow = m0 + wr * 64 + mi * 16 + g * 4 + r;
                if (grow < M)
                    C[(size_t)grow * N + col] = acc[mi][ni][r] + bv;
            }
        }
    }
}

// ---------------- RMS norm + RoPE + concat + bf16 cast ----------------
// ISQ=1: Q path — also premultiplies SM_SCALE (both roped dst and ipq).
template<int ISQ>
__global__ __launch_bounds__(256)
void rmsrope(const float* __restrict__ Pimg, const float* __restrict__ Ptxt,
             int stride, int colofs,
             const float* __restrict__ wimg, const float* __restrict__ wtxt,
             const float* __restrict__ cosb, const float* __restrict__ sinb,
             unsigned short* __restrict__ dst, unsigned short* __restrict__ ipq)
{
    int wg = blockIdx.x * 4 + (threadIdx.x >> 6);
    int lane = threadIdx.x & 63;
    int s = wg / H;
    int h = wg - s * H;
    const float* src = (s < S_TXT) ? (Ptxt + (size_t)s * stride)
                                   : (Pimg + (size_t)(s - S_TXT) * stride);
    src += colofs;
    const float* w = (s < S_TXT) ? wtxt : wimg;
    float2 x = *(const float2*)(src + h * HD + lane * 2);
    float ss = x.x * x.x + x.y * x.y;
    #pragma unroll
    for (int off = 1; off < 64; off <<= 1) ss += __shfl_xor(ss, off);
    float rr = rsqrtf(ss * (1.f / HD) + 1e-6f);
    if (ISQ) rr *= SM_SCALE;
    float xn0 = x.x * rr * w[lane * 2];
    float xn1 = x.y * rr * w[lane * 2 + 1];
    if (ISQ && s >= S_TXT) {
        *(unsigned*)(ipq + (size_t)h * S_IMG * HD + (size_t)(s - S_TXT) * HD + lane * 2) = pk2(xn0, xn1);
    }
    float c0 = cosb[s * HD + lane * 2], c1 = cosb[s * HD + lane * 2 + 1];
    float sn0 = sinb[s * HD + lane * 2], sn1 = sinb[s * HD + lane * 2 + 1];
    float o0 = xn0 * c0 - xn1 * sn0;
    float o1 = xn1 * c1 + xn0 * sn1;
    *(unsigned*)(dst + (size_t)h * S_ALL * HD + (size_t)s * HD + lane * 2) = pk2(o0, o1);
}

// ---------------- V concat + transpose to [H][HD][Stot] bf16 ----------------
__global__ __launch_bounds__(256)
void vtrans(const float* __restrict__ Vimg, const float* __restrict__ Vtxt,
            int stride, int colofs, unsigned short* __restrict__ vt, int Stot)
{
    __shared__ float lv[64 * 129];
    int h = blockIdx.y;
    int s0 = blockIdx.x * 64;
    const float* src = (s0 < S_TXT) ? (Vtxt + (size_t)s0 * stride)
                                    : (Vimg + (size_t)(s0 - S_TXT) * stride);
    src += colofs;
    int tid = threadIdx.x;
    #pragma unroll
    for (int i = 0; i < 8; i++) {
        int slot = tid + 256 * i;
        int row = slot >> 5, c4 = slot & 31;
        float4 v = *(const float4*)(src + (size_t)row * stride + h * HD + c4 * 4);
        float* p = lv + row * 129 + c4 * 4;
        p[0] = v.x; p[1] = v.y; p[2] = v.z; p[3] = v.w;
    }
    __syncthreads();
    #pragma unroll
    for (int i = 0; i < 4; i++) {
        int slot = tid + 256 * i;
        int d = slot >> 3, c8 = slot & 7;
        unsigned q0 = pk2(lv[(c8 * 8 + 0) * 129 + d], lv[(c8 * 8 + 1) * 129 + d]);
        unsigned q1 = pk2(lv[(c8 * 8 + 2) * 129 + d], lv[(c8 * 8 + 3) * 129 + d]);
        unsigned q2 = pk2(lv[(c8 * 8 + 4) * 129 + d], lv[(c8 * 8 + 5) * 129 + d]);
        unsigned q3 = pk2(lv[(c8 * 8 + 6) * 129 + d], lv[(c8 * 8 + 7) * 129 + d]);
        int4 o = {(int)q0, (int)q1, (int)q2, (int)q3};
        *(int4*)(vt + (size_t)(h * HD + d) * Stot + s0 + c8 * 8) = o;
    }
}

// ---------------- cast head-block to [H][N_IP][HD] bf16 ----------------
__global__ __launch_bounds__(256)
void cast_heads(const float* __restrict__ in, int stride, int colofs,
                unsigned short* __restrict__ out)
{
    int idx = blockIdx.x * 256 + threadIdx.x;
    int s = idx / (DMODEL / 2);
    int rem = idx - s * (DMODEL / 2);
    int h = rem / (HD / 2);
    int d2 = rem - h * (HD / 2);
    float2 v = *(const float2*)(in + (size_t)s * stride + colofs + h * HD + d2 * 2);
    *(unsigned*)(out + (size_t)h * N_IP * HD + s * HD + d2 * 2) = pk2(v.x, v.y);
}

// ---------------- Flash attention: 8 warps x 32 q-rows, 32x32x16 MFMA, swapped QK ----------------
// Q pre-scaled by SM_SCALE. K LDS [64][128]bf16 swizzled; Vt LDS [128][64]bf16 swizzled.
// S^T = mfma(K, Q): lane holds P-row for q=lane&31 (kv split across lane-halves).
template<int MODE>  // 0 = IP (write f32), 1 = main (add ip, write bf16)
__global__ __launch_bounds__(512, 2)
void flash2(const unsigned short* __restrict__ Q, const unsigned short* __restrict__ Kb,
            const unsigned short* __restrict__ Vt, const float* __restrict__ ipb,
            void* __restrict__ Out, int Sq, int Skv)
{
    __shared__ char sm[33792];  // K 16K @0, Vt 16K @16384, scl 1K @32768
    const int h = blockIdx.y;
    const int q0 = blockIdx.x * 256;
    const int tid = threadIdx.x, w = tid >> 6, lane = tid & 63;
    const int l31 = lane & 31, hi = lane >> 5;

    // Q fragments (B-operand): lane holds Q[q=l31][d = c*16 + hi*8 .. +8]
    const unsigned short* Qh = Q + ((size_t)h * Sq + q0 + w * 32 + l31) * HD + hi * 8;
    short8 qf[8];
    #pragma unroll
    for (int c = 0; c < 8; c++)
        qf[c] = *(const short8*)(Qh + c * 16);

    float m = -3.0e38f, lsum = 0.f;
    f32x16 o[4];
    #pragma unroll
    for (int dn = 0; dn < 4; dn++)
        #pragma unroll
        for (int r = 0; r < 16; r++) o[dn][r] = 0.f;

    const unsigned short* Kh = Kb + (size_t)h * Skv * HD;
    const unsigned short* Vth = Vt + (size_t)h * HD * Skv;
    float* scl = (float*)(sm + 32768) + w * 32;

    for (int kv0 = 0; kv0 < Skv; kv0 += 64) {
        // stage K tile [64][128] (256B rows, 16 slots) — pre-swizzled source
        #pragma unroll
        for (int cc = 0; cc < 2; cc++) {
            int flat = w * 128 + cc * 64 + lane;
            int row = flat >> 4, slot = flat & 15;
            gload16(Kh + (size_t)(kv0 + row) * HD + (((slot * 16) ^ ((row & 7) << 4)) >> 1),
                    sm + w * 2048 + cc * 1024);
        }
        // stage Vt tile [128][64] (128B rows, 8 slots)
        #pragma unroll
        for (int cc = 0; cc < 2; cc++) {
            int flat = w * 128 + cc * 64 + lane;
            int d = flat >> 3, slot = flat & 7;
            gload16(Vth + (size_t)d * Skv + kv0 + (((slot * 16) ^ ((d & 7) << 4)) >> 1),
                    sm + 16384 + w * 2048 + cc * 1024);
        }
        __syncthreads();

        // QK^T (swapped): st[t2] = S^T tile, rows kv=t2*32+c(reg,hi), cols q=l31
        f32x16 st[2];
        #pragma unroll
        for (int t2 = 0; t2 < 2; t2++) {
            #pragma unroll
            for (int r = 0; r < 16; r++) st[t2][r] = 0.f;
            #pragma unroll
            for (int c = 0; c < 8; c++) {
                int krow = t2 * 32 + l31;
                short8 kf = *(const short8*)(sm + krow * 256 + ((c * 32 + hi * 16) ^ ((krow & 7) << 4)));
                st[t2] = __builtin_amdgcn_mfma_f32_32x32x16_bf16(kf, qf[c], st[t2], 0, 0, 0);
            }
        }
        // softmax over lane's 32 kv values + partner half
        float pmax = st[0][0];
        #pragma unroll
        for (int t2 = 0; t2 < 2; t2++)
            #pragma unroll
            for (int r = 0; r < 16; r++) pmax = fmaxf(pmax, st[t2][r]);
        pmax = fmaxf(pmax, __shfl_xor(pmax, 32));
        float mn = fmaxf(m, pmax);
        float sc = __expf(m - mn);
        m = mn;
        float psum = 0.f;
        #pragma unroll
        for (int t2 = 0; t2 < 2; t2++)
            #pragma unroll
            for (int r = 0; r < 16; r++) {
                float p = __expf(st[t2][r] - mn);
                st[t2][r] = p;
                psum += p;
            }
        psum += __shfl_xor(psum, 32);
        lsum = lsum * sc + psum;
        if (hi == 0) scl[l31] = sc;

        // pack P -> bf16 A-frags: pa[k4] covers kv = k4*16 + hi*8 + 0..7
        short8 pa[4];
        #pragma unroll
        for (int k4 = 0; k4 < 4; k4++) {
            // p[j] = st[j>>4][j&15], j = k4*8 + i
            unsigned U  = pk2(st[(k4 * 8 + 0) >> 4][(k4 * 8 + 0) & 15], st[(k4 * 8 + 1) >> 4][(k4 * 8 + 1) & 15]);
            unsigned V  = pk2(st[(k4 * 8 + 2) >> 4][(k4 * 8 + 2) & 15], st[(k4 * 8 + 3) >> 4][(k4 * 8 + 3) & 15]);
            unsigned U2 = pk2(st[(k4 * 8 + 4) >> 4][(k4 * 8 + 4) & 15], st[(k4 * 8 + 5) >> 4][(k4 * 8 + 5) & 15]);
            unsigned V2 = pk2(st[(k4 * 8 + 6) >> 4][(k4 * 8 + 6) & 15], st[(k4 * 8 + 7) >> 4][(k4 * 8 + 7) & 15]);
            unsigned SU = __shfl_xor(U, 32), SU2 = __shfl_xor(U2, 32);
            unsigned SV = __shfl_xor(V, 32), SV2 = __shfl_xor(V2, 32);
            uint4 wv;
            wv.x = hi ? SU2 : U;
            wv.y = hi ? SV2 : V;
            wv.z = hi ? U2 : SU;
            wv.w = hi ? V2 : SV;
            pa[k4] = __builtin_bit_cast(short8, wv);
        }
        // O rescale (broadcast per-q factors)
        float scb[16];
        #pragma unroll
        for (int r = 0; r < 16; r++)
            scb[r] = scl[(r & 3) + 8 * (r >> 2) + 4 * hi];
        #pragma unroll
        for (int dn = 0; dn < 4; dn++)
            #pragma unroll
            for (int r = 0; r < 16; r++) o[dn][r] *= scb[r];
        // PV: o[dn] += P[q][kv] * V[kv][d], B-frag from Vt LDS
        #pragma unroll
        for (int dn = 0; dn < 4; dn++) {
            #pragma unroll
            for (int k4 = 0; k4 < 4; k4++) {
                int vrow = dn * 32 + l31;
                short8 vf = *(const short8*)(sm + 16384 + vrow * 128 + ((k4 * 32 + hi * 16) ^ ((vrow & 7) << 4)));
                o[dn] = __builtin_amdgcn_mfma_f32_32x32x16_bf16(pa[k4], vf, o[dn], 0, 0, 0);
            }
        }
        __syncthreads();
    }

    // epilogue
    if (hi == 0) scl[l31] = 1.f / lsum;
    float linv[16];
    #pragma unroll
    for (int r = 0; r < 16; r++)
        linv[r] = scl[(r & 3) + 8 * (r >> 2) + 4 * hi];
    #pragma unroll
    for (int dn = 0; dn < 4; dn++) {
        #pragma unroll
        for (int r = 0; r < 16; r++) {
            int qrow = q0 + w * 32 + (r & 3) + 8 * (r >> 2) + 4 * hi;
            int col = h * HD + dn * 32 + l31;
            float val = o[dn][r] * linv[r];
            if (MODE == 0) {
                ((float*)Out)[(size_t)qrow * DMODEL + col] = val;
            } else {
                if (qrow >= S_TXT) val += ipb[(size_t)(qrow - S_TXT) * DMODEL + col];
                ((unsigned short*)Out)[(size_t)qrow * DMODEL + col] = f2bf(val);
            }
        }
    }
}

// ---------------- launch ----------------
extern "C" void kernel_launch(void* const* d_in, const int* in_sizes, int n_in,
                              void* d_out, int out_size, void* d_ws, size_t ws_size,
                              hipStream_t stream)
{
    const float* hs   = (const float*)d_in[0];
    const float* enc  = (const float*)d_in[1];
    const float* iemb = (const float*)d_in[2];
    const float* cosb = (const float*)d_in[3];
    const float* sinb = (const float*)d_in[4];
    const float* Wq  = (const float*)d_in[5];  const float* bq  = (const float*)d_in[6];
    const float* Wk  = (const float*)d_in[7];  const float* bk  = (const float*)d_in[8];
    const float* Wv  = (const float*)d_in[9];  const float* bv  = (const float*)d_in[10];
    const float* Waq = (const float*)d_in[11]; const float* baq = (const float*)d_in[12];
    const float* Wak = (const float*)d_in[13]; const float* bak = (const float*)d_in[14];
    const float* Wav = (const float*)d_in[15]; const float* bav = (const float*)d_in[16];
    const float* Wo  = (const float*)d_in[17]; const float* bo  = (const float*)d_in[18];
    const float* Wao = (const float*)d_in[19]; const float* bao = (const float*)d_in[20];
    const float* nq  = (const float*)d_in[21]; const float* nk  = (const float*)d_in[22];
    const float* naq = (const float*)d_in[23]; const float* nak = (const float*)d_in[24];
    const float* Wkip = (const float*)d_in[25]; const float* Wvip = (const float*)d_in[26];
    (void)in_sizes; (void)n_in; (void)out_size; (void)ws_size;

    char* ws = (char*)d_ws;
    size_t off = 0;
    auto alloc = [&](size_t b) { char* p = ws + off; off += (b + 255) & ~(size_t)255; return p; };
    float* qkv_img = (float*)alloc((size_t)S_IMG * 3 * DMODEL * 4);
    float* qkv_txt = (float*)alloc((size_t)S_TXT * 3 * DMODEL * 4);
    float* ipkv    = (float*)alloc((size_t)128 * 2 * DMODEL * 4);
    unsigned short* hs_bf   = (unsigned short*)alloc((size_t)S_IMG * DMODEL * 2);
    unsigned short* enc_bf  = (unsigned short*)alloc((size_t)S_TXT * DMODEL * 2);
    unsigned short* iemb_bf = (unsigned short*)alloc((size_t)128 * EMB * 2);
    unsigned short* Wqkv  = (unsigned short*)alloc((size_t)3 * DMODEL * DMODEL * 2);
    unsigned short* Waqkv = (unsigned short*)alloc((size_t)3 * DMODEL * DMODEL * 2);
    unsigned short* Wo_b  = (unsigned short*)alloc((size_t)DMODEL * DMODEL * 2);
    unsigned short* Wao_b = (unsigned short*)alloc((size_t)DMODEL * DMODEL * 2);
    unsigned short* Wip   = (unsigned short*)alloc((size_t)2 * DMODEL * EMB * 2);
    float* bqkv  = (float*)alloc(3 * DMODEL * 4);
    float* baqkv = (float*)alloc(3 * DMODEL * 4);
    unsigned short* qb    = (unsigned short*)alloc((size_t)H * S_ALL * HD * 2);
    unsigned short* kbf   = (unsigned short*)alloc((size_t)H * S_ALL * HD * 2);
    unsigned short* vtb   = (unsigned short*)alloc((size_t)H * HD * S_ALL * 2);
    unsigned short* ipqb  = (unsigned short*)alloc((size_t)H * S_IMG * HD * 2);
    unsigned short* ipkb  = (unsigned short*)alloc((size_t)H * N_IP * HD * 2);
    unsigned short* ipvtb = (unsigned short*)alloc((size_t)H * HD * N_IP * 2);
    float* ipbuf = qkv_img;
    unsigned short* attnb = (unsigned short*)qkv_txt;

    dim3 blk(256);
    const int D2 = DMODEL * DMODEL / 8;
    castk<<<1024, blk, 0, stream>>>(hs,   hs_bf,   S_IMG * DMODEL / 8, S_IMG * DMODEL / 8);
    castk<<<256,  blk, 0, stream>>>(enc,  enc_bf,  S_TXT * DMODEL / 8, S_TXT * DMODEL / 8);
    castk<<<128,  blk, 0, stream>>>(iemb, iemb_bf, N_IP * EMB / 8, 128 * EMB / 8);
    castk<<<1024, blk, 0, stream>>>(Wq,  Wqkv,              D2, D2);
    castk<<<1024, blk, 0, stream>>>(Wk,  Wqkv + (size_t)DMODEL * DMODEL,     D2, D2);
    castk<<<1024, blk, 0, stream>>>(Wv,  Wqkv + (size_t)2 * DMODEL * DMODEL, D2, D2);
    castk<<<1024, blk, 0, stream>>>(Waq, Waqkv,             D2, D2);
    castk<<<1024, blk, 0, stream>>>(Wak, Waqkv + (size_t)DMODEL * DMODEL,     D2, D2);
    castk<<<1024, blk, 0, stream>>>(Wav, Waqkv + (size_t)2 * DMODEL * DMODEL, D2, D2);
    castk<<<1024, blk, 0, stream>>>(Wo,  Wo_b,  D2, D2);
    castk<<<1024, blk, 0, stream>>>(Wao, Wao_b, D2, D2);
    castk<<<1024, blk, 0, stream>>>(Wkip, Wip,                        DMODEL * EMB / 8, DMODEL * EMB / 8);
    castk<<<1024, blk, 0, stream>>>(Wvip, Wip + (size_t)DMODEL * EMB, DMODEL * EMB / 8, DMODEL * EMB / 8);
    bcat3<<<36, blk, 0, stream>>>(bq, bk, bv, bqkv);
    bcat3<<<36, blk, 0, stream>>>(baq, bak, bav, baqkv);

    gemm16<<<dim3(16 * 72), blk, 0, stream>>>(hs_bf,  Wqkv,  bqkv,  qkv_img, S_IMG, 3 * DMODEL, DMODEL, 72);
    gemm16<<<dim3(4 * 72),  blk, 0, stream>>>(enc_bf, Waqkv, baqkv, qkv_txt, S_TXT, 3 * DMODEL, DMODEL, 72);
    gemm16<<<dim3(1 * 48),  blk, 0, stream>>>(iemb_bf, Wip, nullptr, ipkv, 128, 2 * DMODEL, EMB, 48);

    rmsrope<1><<<dim3(15360), blk, 0, stream>>>(qkv_img, qkv_txt, 3 * DMODEL, 0,      nq, naq, cosb, sinb, qb, ipqb);
    rmsrope<0><<<dim3(15360), blk, 0, stream>>>(qkv_img, qkv_txt, 3 * DMODEL, DMODEL, nk, nak, cosb, sinb, kbf, nullptr);
    vtrans<<<dim3(40, 24), blk, 0, stream>>>(qkv_img, qkv_txt, 3 * DMODEL, 2 * DMODEL, vtb, S_ALL);
    cast_heads<<<dim3(384), blk, 0, stream>>>(ipkv, 2 * DMODEL, 0, ipkb);
    vtrans<<<dim3(1, 24), blk, 0, stream>>>(ipkv, ipkv, 2 * DMODEL, DMODEL, ipvtb, N_IP);

    dim3 fblk(512);
    flash2<0><<<dim3(8, 24),  fblk, 0, stream>>>(ipqb, ipkb, ipvtb, nullptr, ipbuf, S_IMG, N_IP);
    flash2<1><<<dim3(10, 24), fblk, 0, stream>>>(qb, kbf, vtb, ipbuf, attnb, S_ALL, S_ALL);

    float* dout = (float*)d_out;
    gemm16<<<dim3(16 * 24), blk, 0, stream>>>(attnb + (size_t)S_TXT * DMODEL, Wo_b, bo, dout, S_IMG, DMODEL, DMODEL, 24);
    gemm16<<<dim3(4 * 24),  blk, 0, stream>>>(attnb, Wao_b, bao, dout + (size_t)S_IMG * DMODEL, S_TXT, DMODEL, DMODEL, 24);
}

// Round 4
// 664.820 us; speedup vs baseline: 3.6218x; 1.2882x over previous
//
#include <hip/hip_runtime.h>
#include <hip/hip_bf16.h>

#define H 24
#define HD 128
#define DMODEL 3072
#define S_IMG 2048
#define S_TXT 512
#define S_ALL 2560
#define EMB 4096
#define N_IP 64
#define SM_SCALE 0.08838834764831845f  // 1/sqrt(128)

typedef __attribute__((ext_vector_type(8))) short short8;
typedef __attribute__((ext_vector_type(4))) float f32x4;
typedef __attribute__((ext_vector_type(16))) float f32x16;

__device__ inline unsigned short f2bf(float f) {
    unsigned u = __builtin_bit_cast(unsigned, f);
    return (unsigned short)((u + 0x7fffu + ((u >> 16) & 1u)) >> 16);
}
__device__ inline unsigned pk2(float a, float b) {
    return (unsigned)f2bf(a) | ((unsigned)f2bf(b) << 16);
}
__device__ inline float bf2f(unsigned short u) {
    unsigned x = ((unsigned)u) << 16;
    return __builtin_bit_cast(float, x);
}

__device__ inline void gload16(const void* g, void* l) {
    __builtin_amdgcn_global_load_lds(
        (const __attribute__((address_space(1))) unsigned int*)g,
        (__attribute__((address_space(3))) unsigned int*)(unsigned int)(unsigned long long)l,
        16, 0, 0);
}

// ---------------- merged f32 -> bf16 casts (13 segments, one dispatch) ----------------
struct CastSegs {
    const float* src[13];
    unsigned short* dst[13];
    int n8[13];
    int ntot8[13];
    int bstart[14];
};

__global__ __launch_bounds__(256)
void castall(CastSegs cs)
{
    int b = blockIdx.x, seg = 0;
    while (seg < 12 && b >= cs.bstart[seg + 1]) seg++;
    int nb = cs.bstart[seg + 1] - cs.bstart[seg];
    int lb = b - cs.bstart[seg];
    const float* in = cs.src[seg];
    unsigned short* out = cs.dst[seg];
    int n8 = cs.n8[seg], ntot = cs.ntot8[seg];
    for (int i = lb * 256 + threadIdx.x; i < ntot; i += nb * 256) {
        int4 o;
        if (i < n8) {
            const float4* p = (const float4*)(in + (size_t)i * 8);
            float4 a = p[0], bb = p[1];
            o.x = pk2(a.x, a.y); o.y = pk2(a.z, a.w);
            o.z = pk2(bb.x, bb.y); o.w = pk2(bb.z, bb.w);
        } else {
            o.x = 0; o.y = 0; o.z = 0; o.w = 0;
        }
        *(int4*)(out + (size_t)i * 8) = o;
    }
}

__global__ __launch_bounds__(256)
void bcat2(const float* __restrict__ q0, const float* __restrict__ k0, const float* __restrict__ v0,
           const float* __restrict__ q1, const float* __restrict__ k1, const float* __restrict__ v1,
           float* __restrict__ d0, float* __restrict__ d1)
{
    int i = blockIdx.x * 256 + threadIdx.x;  // 18432
    int which = i >= 3 * DMODEL;
    int j = which ? i - 3 * DMODEL : i;
    const float* a = which ? q1 : q0;
    const float* b = which ? k1 : k0;
    const float* c = which ? v1 : v0;
    float v = (j < DMODEL) ? a[j] : ((j < 2 * DMODEL) ? b[j - DMODEL] : c[j - 2 * DMODEL]);
    (which ? d1 : d0)[j] = v;
}

// ---------------- GEMM (m97 structure, GN-grouped XCD regions, dual-routed) ----------------
// C = A @ B^T + bias; 128x128 tile, BK=64. Blocks with mb < mbSplit use set0, else set1.
// Grid = nbm*nbn, %8==0; nbn = GN*8 (one group == one XCD chunk), mb-fastest in group.
template<int OUTBF>
__global__ __launch_bounds__(256)
void gemmx(const unsigned short* __restrict__ A0, const unsigned short* __restrict__ B0,
           const float* __restrict__ b0, void* __restrict__ C0,
           const unsigned short* __restrict__ A1, const unsigned short* __restrict__ B1,
           const float* __restrict__ b1, void* __restrict__ C1,
           int mbSplit, int N, int K, int nbm, int GN)
{
    __shared__ unsigned short sm[2 * 8192];
    const int tid = threadIdx.x, lane = tid & 63, wid = tid >> 6;
    const int wr = wid >> 1, wc = wid & 1;
    const int r15 = lane & 15, g = lane >> 4;

    int nwg = gridDim.x;
    int t = (blockIdx.x & 7) * (nwg >> 3) + (blockIdx.x >> 3);
    int gsz = nbm * GN;
    int G = t / gsz, l = t - G * gsz;
    int mb = l % nbm, nb = G * GN + l / nbm;

    const unsigned short* A; const unsigned short* B; const float* bias; void* C; int mrow;
    if (mb < mbSplit) { A = A0; B = B0; bias = b0; C = C0; mrow = mb; }
    else             { A = A1; B = B1; bias = b1; C = C1; mrow = mb - mbSplit; }
    const int m0 = mrow * 128, n0 = nb * 128;

    const int lr = lane >> 3;
    const int lc = lane & 7;
    const int gcol = ((lc * 16) ^ (lr << 4)) >> 1;

    const unsigned short* Ab = A + (size_t)(m0 + wid * 32 + lr) * K + gcol;
    const unsigned short* Bb = B + (size_t)(n0 + wid * 32 + lr) * K + gcol;
    char* smc = (char*)sm;

    f32x4 acc[4][4];
    #pragma unroll
    for (int i = 0; i < 4; i++)
        #pragma unroll
        for (int j = 0; j < 4; j++)
            acc[i][j] = {0.f, 0.f, 0.f, 0.f};

    for (int k0 = 0; k0 < K; k0 += 64) {
        #pragma unroll
        for (int cc = 0; cc < 4; cc++) {
            gload16(Ab + (size_t)cc * 8 * K + k0, smc + (wid * 32 + cc * 8) * 128);
            gload16(Bb + (size_t)cc * 8 * K + k0, smc + 16384 + (wid * 32 + cc * 8) * 128);
        }
        __syncthreads();
        #pragma unroll
        for (int ks = 0; ks < 2; ks++) {
            short8 af[4], bf[4];
            #pragma unroll
            for (int mi = 0; mi < 4; mi++) {
                int row = wr * 64 + mi * 16 + r15;
                af[mi] = *(const short8*)(smc + row * 128 + ((ks * 64 + g * 16) ^ ((row & 7) << 4)));
            }
            #pragma unroll
            for (int ni = 0; ni < 4; ni++) {
                int row = wc * 64 + ni * 16 + r15;
                bf[ni] = *(const short8*)(smc + 16384 + row * 128 + ((ks * 64 + g * 16) ^ ((row & 7) << 4)));
            }
            #pragma unroll
            for (int mi = 0; mi < 4; mi++)
                #pragma unroll
                for (int ni = 0; ni < 4; ni++)
                    acc[mi][ni] = __builtin_amdgcn_mfma_f32_16x16x32_bf16(af[mi], bf[ni], acc[mi][ni], 0, 0, 0);
        }
        __syncthreads();
    }
    #pragma unroll
    for (int mi = 0; mi < 4; mi++) {
        #pragma unroll
        for (int ni = 0; ni < 4; ni++) {
            int col = n0 + wc * 64 + ni * 16 + r15;
            float bv = bias ? bias[col] : 0.f;
            #pragma unroll
            for (int r = 0; r < 4; r++) {
                int grow = m0 + wr * 64 + mi * 16 + g * 4 + r;
                float v = acc[mi][ni][r] + bv;
                if (OUTBF)
                    ((unsigned short*)C)[(size_t)grow * N + col] = f2bf(v);
                else
                    ((float*)C)[(size_t)grow * N + col] = v;
            }
        }
    }
}

// ---------------- fused RMS norm + RoPE for Q and K (bf16 in, bf16 out) ----------------
__global__ __launch_bounds__(256)
void rmsropeQK(const unsigned short* __restrict__ qkvb,
               const float* __restrict__ nqw, const float* __restrict__ nkw,
               const float* __restrict__ naqw, const float* __restrict__ nakw,
               const float* __restrict__ cosb, const float* __restrict__ sinb,
               unsigned short* __restrict__ qb, unsigned short* __restrict__ kb,
               unsigned short* __restrict__ ipq)
{
    int wg = blockIdx.x * 4 + (threadIdx.x >> 6);
    int lane = threadIdx.x & 63;
    int s = wg / H, h = wg - s * H;
    const unsigned short* row = qkvb + (size_t)s * (3 * DMODEL);
    unsigned uq = *(const unsigned*)(row + h * HD + lane * 2);
    unsigned uk = *(const unsigned*)(row + DMODEL + h * HD + lane * 2);
    float q0 = bf2f((unsigned short)uq), q1 = bf2f((unsigned short)(uq >> 16));
    float k0 = bf2f((unsigned short)uk), k1 = bf2f((unsigned short)(uk >> 16));
    float sq = q0 * q0 + q1 * q1, sk = k0 * k0 + k1 * k1;
    #pragma unroll
    for (int off = 1; off < 64; off <<= 1) {
        sq += __shfl_xor(sq, off);
        sk += __shfl_xor(sk, off);
    }
    float rq = rsqrtf(sq * (1.f / HD) + 1e-6f) * SM_SCALE;
    float rk = rsqrtf(sk * (1.f / HD) + 1e-6f);
    const float* wq = (s < S_TXT) ? naqw : nqw;
    const float* wk = (s < S_TXT) ? nakw : nkw;
    float xq0 = q0 * rq * wq[lane * 2], xq1 = q1 * rq * wq[lane * 2 + 1];
    float xk0 = k0 * rk * wk[lane * 2], xk1 = k1 * rk * wk[lane * 2 + 1];
    if (s >= S_TXT)
        *(unsigned*)(ipq + (size_t)h * S_IMG * HD + (size_t)(s - S_TXT) * HD + lane * 2) = pk2(xq0, xq1);
    float c0 = cosb[s * HD + lane * 2], c1 = cosb[s * HD + lane * 2 + 1];
    float s0 = sinb[s * HD + lane * 2], s1 = sinb[s * HD + lane * 2 + 1];
    *(unsigned*)(qb + (size_t)h * S_ALL * HD + (size_t)s * HD + lane * 2) =
        pk2(xq0 * c0 - xq1 * s0, xq1 * c1 + xq0 * s1);
    *(unsigned*)(kb + (size_t)h * S_ALL * HD + (size_t)s * HD + lane * 2) =
        pk2(xk0 * c0 - xk1 * s0, xk1 * c1 + xk0 * s1);
}

// ---------------- V transpose: bf16 [S][stride] (col block h*HD) -> [H][HD][Stot] ----------------
__global__ __launch_bounds__(256)
void vtrans(const unsigned short* __restrict__ src, int stride,
            unsigned short* __restrict__ vt, int Stot)
{
    __shared__ unsigned short lv[64 * 130];
    int h = blockIdx.y;
    int s0 = blockIdx.x * 64;
    const unsigned short* base = src + (size_t)s0 * stride + h * HD;
    int tid = threadIdx.x;
    #pragma unroll
    for (int i = 0; i < 4; i++) {
        int slot = tid + 256 * i;           // 1024: row 0..63, 16B-chunk 0..15
        int row = slot >> 4, c = slot & 15;
        int4 v = *(const int4*)(base + (size_t)row * stride + c * 8);
        unsigned* p = (unsigned*)(lv + row * 130 + c * 8);  // 4B-aligned stores
        p[0] = (unsigned)v.x; p[1] = (unsigned)v.y; p[2] = (unsigned)v.z; p[3] = (unsigned)v.w;
    }
    __syncthreads();
    #pragma unroll
    for (int i = 0; i < 4; i++) {
        int slot = tid + 256 * i;           // 1024: d 0..127, 8-col chunk 0..7
        int d = slot >> 3, c8 = slot & 7;
        unsigned w0 = lv[(c8 * 8 + 0) * 130 + d] | ((unsigned)lv[(c8 * 8 + 1) * 130 + d] << 16);
        unsigned w1 = lv[(c8 * 8 + 2) * 130 + d] | ((unsigned)lv[(c8 * 8 + 3) * 130 + d] << 16);
        unsigned w2 = lv[(c8 * 8 + 4) * 130 + d] | ((unsigned)lv[(c8 * 8 + 5) * 130 + d] << 16);
        unsigned w3 = lv[(c8 * 8 + 6) * 130 + d] | ((unsigned)lv[(c8 * 8 + 7) * 130 + d] << 16);
        int4 o = {(int)w0, (int)w1, (int)w2, (int)w3};
        *(int4*)(vt + (size_t)(h * HD + d) * Stot + s0 + c8 * 8) = o;
    }
}

// ---------------- relayout ip K: [N_IP][2*DMODEL] bf16 -> [H][N_IP][HD] bf16 ----------------
__global__ __launch_bounds__(256)
void cast_heads8(const unsigned short* __restrict__ in, unsigned short* __restrict__ out)
{
    int idx = blockIdx.x * 256 + threadIdx.x;   // 24576 = N_IP * DMODEL / 8
    int s = idx / 384;
    int rem = idx - s * 384;
    int h = rem >> 4, d8 = rem & 15;
    int4 v = *(const int4*)(in + (size_t)s * (2 * DMODEL) + h * HD + d8 * 8);
    *(int4*)(out + ((size_t)h * N_IP + s) * HD + d8 * 8) = v;
}

// ---------------- Flash attention: 8 warps x 32 q-rows, 32x32x16 MFMA, swapped QK ----------------
template<int MODE>  // 0 = IP (write bf16 ip_hs), 1 = main (add bf16 ip, write bf16)
__global__ __launch_bounds__(512, 2)
void flash2(const unsigned short* __restrict__ Q, const unsigned short* __restrict__ Kb,
            const unsigned short* __restrict__ Vt, const unsigned short* __restrict__ ipb,
            unsigned short* __restrict__ Out, int Sq, int Skv)
{
    __shared__ char sm[33792];  // K 16K @0, Vt 16K @16384, scl 1K @32768
    const int h = blockIdx.y;
    const int q0 = blockIdx.x * 256;
    const int tid = threadIdx.x, w = tid >> 6, lane = tid & 63;
    const int l31 = lane & 31, hi = lane >> 5;

    const unsigned short* Qh = Q + ((size_t)h * Sq + q0 + w * 32 + l31) * HD + hi * 8;
    short8 qf[8];
    #pragma unroll
    for (int c = 0; c < 8; c++)
        qf[c] = *(const short8*)(Qh + c * 16);

    float m = -3.0e38f, lsum = 0.f;
    f32x16 o[4];
    #pragma unroll
    for (int dn = 0; dn < 4; dn++)
        #pragma unroll
        for (int r = 0; r < 16; r++) o[dn][r] = 0.f;

    const unsigned short* Kh = Kb + (size_t)h * Skv * HD;
    const unsigned short* Vth = Vt + (size_t)h * HD * Skv;
    float* scl = (float*)(sm + 32768) + w * 32;

    for (int kv0 = 0; kv0 < Skv; kv0 += 64) {
        #pragma unroll
        for (int cc = 0; cc < 2; cc++) {
            int flat = w * 128 + cc * 64 + lane;
            int row = flat >> 4, slot = flat & 15;
            gload16(Kh + (size_t)(kv0 + row) * HD + (((slot * 16) ^ ((row & 7) << 4)) >> 1),
                    sm + w * 2048 + cc * 1024);
        }
        #pragma unroll
        for (int cc = 0; cc < 2; cc++) {
            int flat = w * 128 + cc * 64 + lane;
            int d = flat >> 3, slot = flat & 7;
            gload16(Vth + (size_t)d * Skv + kv0 + (((slot * 16) ^ ((d & 7) << 4)) >> 1),
                    sm + 16384 + w * 2048 + cc * 1024);
        }
        __syncthreads();

        f32x16 st[2];
        __builtin_amdgcn_s_setprio(1);
        #pragma unroll
        for (int t2 = 0; t2 < 2; t2++) {
            #pragma unroll
            for (int r = 0; r < 16; r++) st[t2][r] = 0.f;
            #pragma unroll
            for (int c = 0; c < 8; c++) {
                int krow = t2 * 32 + l31;
                short8 kf = *(const short8*)(sm + krow * 256 + ((c * 32 + hi * 16) ^ ((krow & 7) << 4)));
                st[t2] = __builtin_amdgcn_mfma_f32_32x32x16_bf16(kf, qf[c], st[t2], 0, 0, 0);
            }
        }
        __builtin_amdgcn_s_setprio(0);
        float pmax = st[0][0];
        #pragma unroll
        for (int t2 = 0; t2 < 2; t2++)
            #pragma unroll
            for (int r = 0; r < 16; r++) pmax = fmaxf(pmax, st[t2][r]);
        pmax = fmaxf(pmax, __shfl_xor(pmax, 32));
        float mn = fmaxf(m, pmax);
        float sc = __expf(m - mn);
        m = mn;
        float psum = 0.f;
        #pragma unroll
        for (int t2 = 0; t2 < 2; t2++)
            #pragma unroll
            for (int r = 0; r < 16; r++) {
                float p = __expf(st[t2][r] - mn);
                st[t2][r] = p;
                psum += p;
            }
        psum += __shfl_xor(psum, 32);
        lsum = lsum * sc + psum;
        if (hi == 0) scl[l31] = sc;

        short8 pa[4];
        #pragma unroll
        for (int k4 = 0; k4 < 4; k4++) {
            unsigned U  = pk2(st[(k4 * 8 + 0) >> 4][(k4 * 8 + 0) & 15], st[(k4 * 8 + 1) >> 4][(k4 * 8 + 1) & 15]);
            unsigned V  = pk2(st[(k4 * 8 + 2) >> 4][(k4 * 8 + 2) & 15], st[(k4 * 8 + 3) >> 4][(k4 * 8 + 3) & 15]);
            unsigned U2 = pk2(st[(k4 * 8 + 4) >> 4][(k4 * 8 + 4) & 15], st[(k4 * 8 + 5) >> 4][(k4 * 8 + 5) & 15]);
            unsigned V2 = pk2(st[(k4 * 8 + 6) >> 4][(k4 * 8 + 6) & 15], st[(k4 * 8 + 7) >> 4][(k4 * 8 + 7) & 15]);
            unsigned SU = __shfl_xor(U, 32), SU2 = __shfl_xor(U2, 32);
            unsigned SV = __shfl_xor(V, 32), SV2 = __shfl_xor(V2, 32);
            uint4 wv;
            wv.x = hi ? SU2 : U;
            wv.y = hi ? SV2 : V;
            wv.z = hi ? U2 : SU;
            wv.w = hi ? V2 : SV;
            pa[k4] = __builtin_bit_cast(short8, wv);
        }
        float scb[16];
        #pragma unroll
        for (int r = 0; r < 16; r++)
            scb[r] = scl[(r & 3) + 8 * (r >> 2) + 4 * hi];
        #pragma unroll
        for (int dn = 0; dn < 4; dn++)
            #pragma unroll
            for (int r = 0; r < 16; r++) o[dn][r] *= scb[r];
        __builtin_amdgcn_s_setprio(1);
        #pragma unroll
        for (int dn = 0; dn < 4; dn++) {
            #pragma unroll
            for (int k4 = 0; k4 < 4; k4++) {
                int vrow = dn * 32 + l31;
                short8 vf = *(const short8*)(sm + 16384 + vrow * 128 + ((k4 * 32 + hi * 16) ^ ((vrow & 7) << 4)));
                o[dn] = __builtin_amdgcn_mfma_f32_32x32x16_bf16(pa[k4], vf, o[dn], 0, 0, 0);
            }
        }
        __builtin_amdgcn_s_setprio(0);
        __syncthreads();
    }

    if (hi == 0) scl[l31] = 1.f / lsum;
    float linv[16];
    #pragma unroll
    for (int r = 0; r < 16; r++)
        linv[r] = scl[(r & 3) + 8 * (r >> 2) + 4 * hi];
    #pragma unroll
    for (int dn = 0; dn < 4; dn++) {
        #pragma unroll
        for (int r = 0; r < 16; r++) {
            int qrow = q0 + w * 32 + (r & 3) + 8 * (r >> 2) + 4 * hi;
            int col = h * HD + dn * 32 + l31;
            float val = o[dn][r] * linv[r];
            if (MODE == 1 && qrow >= S_TXT)
                val += bf2f(ipb[(size_t)(qrow - S_TXT) * DMODEL + col]);
            Out[(size_t)qrow * DMODEL + col] = f2bf(val);
        }
    }
}

// ---------------- launch ----------------
extern "C" void kernel_launch(void* const* d_in, const int* in_sizes, int n_in,
                              void* d_out, int out_size, void* d_ws, size_t ws_size,
                              hipStream_t stream)
{
    const float* hs   = (const float*)d_in[0];
    const float* enc  = (const float*)d_in[1];
    const float* iemb = (const float*)d_in[2];
    const float* cosb = (const float*)d_in[3];
    const float* sinb = (const float*)d_in[4];
    const float* Wq  = (const float*)d_in[5];  const float* bq  = (const float*)d_in[6];
    const float* Wk  = (const float*)d_in[7];  const float* bk  = (const float*)d_in[8];
    const float* Wv  = (const float*)d_in[9];  const float* bv  = (const float*)d_in[10];
    const float* Waq = (const float*)d_in[11]; const float* baq = (const float*)d_in[12];
    const float* Wak = (const float*)d_in[13]; const float* bak = (const float*)d_in[14];
    const float* Wav = (const float*)d_in[15]; const float* bav = (const float*)d_in[16];
    const float* Wo  = (const float*)d_in[17]; const float* bo  = (const float*)d_in[18];
    const float* Wao = (const float*)d_in[19]; const float* bao = (const float*)d_in[20];
    const float* nq  = (const float*)d_in[21]; const float* nk  = (const float*)d_in[22];
    const float* naq = (const float*)d_in[23]; const float* nak = (const float*)d_in[24];
    const float* Wkip = (const float*)d_in[25]; const float* Wvip = (const float*)d_in[26];
    (void)in_sizes; (void)n_in; (void)out_size; (void)ws_size;

    char* ws = (char*)d_ws;
    size_t off = 0;
    auto alloc = [&](size_t b) { char* p = ws + off; off += (b + 255) & ~(size_t)255; return p; };
    unsigned short* qkvb    = (unsigned short*)alloc((size_t)S_ALL * 3 * DMODEL * 2);  // rows: txt 0..511, img 512..2559
    unsigned short* ipkvb   = (unsigned short*)alloc((size_t)128 * 2 * DMODEL * 2);
    unsigned short* hs_bf   = (unsigned short*)alloc((size_t)S_IMG * DMODEL * 2);
    unsigned short* enc_bf  = (unsigned short*)alloc((size_t)S_TXT * DMODEL * 2);
    unsigned short* iemb_bf = (unsigned short*)alloc((size_t)128 * EMB * 2);
    unsigned short* Wqkv  = (unsigned short*)alloc((size_t)3 * DMODEL * DMODEL * 2);
    unsigned short* Waqkv = (unsigned short*)alloc((size_t)3 * DMODEL * DMODEL * 2);
    unsigned short* Wo_b  = (unsigned short*)alloc((size_t)DMODEL * DMODEL * 2);
    unsigned short* Wao_b = (unsigned short*)alloc((size_t)DMODEL * DMODEL * 2);
    unsigned short* Wip   = (unsigned short*)alloc((size_t)2 * DMODEL * EMB * 2);
    float* bqkv  = (float*)alloc(3 * DMODEL * 4);
    float* baqkv = (float*)alloc(3 * DMODEL * 4);
    unsigned short* qb    = (unsigned short*)alloc((size_t)H * S_ALL * HD * 2);
    unsigned short* kbf   = (unsigned short*)alloc((size_t)H * S_ALL * HD * 2);
    unsigned short* vtb   = (unsigned short*)alloc((size_t)H * HD * S_ALL * 2);
    unsigned short* ipqb  = (unsigned short*)alloc((size_t)H * S_IMG * HD * 2);
    unsigned short* ipkb  = (unsigned short*)alloc((size_t)H * N_IP * HD * 2);
    unsigned short* ipvtb = (unsigned short*)alloc((size_t)H * HD * N_IP * 2);
    unsigned short* ipbuf = (unsigned short*)alloc((size_t)S_IMG * DMODEL * 2);
    unsigned short* attnb = (unsigned short*)alloc((size_t)S_ALL * DMODEL * 2);

    const size_t DD = (size_t)DMODEL * DMODEL;
    const size_t DE = (size_t)DMODEL * EMB;
    const int D8 = (int)(DD / 8), E8 = (int)(DE / 8);

    // merged cast dispatch
    CastSegs cs;
    const float* srcs[13] = {hs, enc, iemb, Wq, Wk, Wv, Waq, Wak, Wav, Wo, Wao, Wkip, Wvip};
    unsigned short* dsts[13] = {hs_bf, enc_bf, iemb_bf,
                                Wqkv, Wqkv + DD, Wqkv + 2 * DD,
                                Waqkv, Waqkv + DD, Waqkv + 2 * DD,
                                Wo_b, Wao_b, Wip, Wip + DE};
    int n8s[13]  = {S_IMG * DMODEL / 8, S_TXT * DMODEL / 8, N_IP * EMB / 8,
                    D8, D8, D8, D8, D8, D8, D8, D8, E8, E8};
    int nt8s[13] = {S_IMG * DMODEL / 8, S_TXT * DMODEL / 8, 128 * EMB / 8,
                    D8, D8, D8, D8, D8, D8, D8, D8, E8, E8};
    int acc = 0;
    for (int i = 0; i < 13; i++) {
        cs.src[i] = srcs[i]; cs.dst[i] = dsts[i];
        cs.n8[i] = n8s[i]; cs.ntot8[i] = nt8s[i];
        cs.bstart[i] = acc;
        int nb = (nt8s[i] + 8191) / 8192;
        acc += (nb < 1 ? 1 : nb);
    }
    cs.bstart[13] = acc;

    dim3 blk(256);
    castall<<<dim3(acc), blk, 0, stream>>>(cs);
    bcat2<<<dim3(72), blk, 0, stream>>>(bq, bk, bv, baq, bak, bav, bqkv, baqkv);

    // merged QKV projections: set0 = img (mb<16), set1 = txt
    gemmx<1><<<dim3(20 * 72), blk, 0, stream>>>(
        hs_bf, Wqkv, bqkv, qkvb + (size_t)S_TXT * 3 * DMODEL,
        enc_bf, Waqkv, baqkv, qkvb,
        16, 3 * DMODEL, DMODEL, 20, 9);
    // ip projections
    gemmx<1><<<dim3(48), blk, 0, stream>>>(
        iemb_bf, Wip, nullptr, ipkvb,
        iemb_bf, Wip, nullptr, ipkvb,
        1, 2 * DMODEL, EMB, 1, 6);

    rmsropeQK<<<dim3(15360), blk, 0, stream>>>(qkvb, nq, nk, naq, nak, cosb, sinb, qb, kbf, ipqb);
    vtrans<<<dim3(40, 24), blk, 0, stream>>>(qkvb + 2 * DMODEL, 3 * DMODEL, vtb, S_ALL);
    cast_heads8<<<dim3(96), blk, 0, stream>>>(ipkvb, ipkb);
    vtrans<<<dim3(1, 24), blk, 0, stream>>>(ipkvb + DMODEL, 2 * DMODEL, ipvtb, N_IP);

    dim3 fblk(512);
    flash2<0><<<dim3(8, 24),  fblk, 0, stream>>>(ipqb, ipkb, ipvtb, nullptr, ipbuf, S_IMG, N_IP);
    flash2<1><<<dim3(10, 24), fblk, 0, stream>>>(qb, kbf, vtb, ipbuf, attnb, S_ALL, S_ALL);

    // merged output projections: set0 = txt (mb<4) -> Wao, set1 = img -> Wo
    float* dout = (float*)d_out;
    gemmx<0><<<dim3(20 * 24), blk, 0, stream>>>(
        attnb, Wao_b, bao, dout + (size_t)S_IMG * DMODEL,
        attnb + (size_t)S_TXT * DMODEL, Wo_b, bo, dout,
        4, DMODEL, DMODEL, 20, 3);
}